// Round 3
// baseline (51.674 us; speedup 1.0000x reference)
//
#include <hip/hip_runtime.h>

#define EPSF 1e-8f
#define PROB_PENALTYF 1e-4f
#define REV_SCALEF 0.1f

#define BLK 256
#define P 8
#define JU 4
#define INFBITS 0x7F800000u

// sentinel "far away" vertex for tile padding: d2 contribution ~3e12, never the min,
// no overflow/NaN even for masked points (px=0 -> s = 3e12).
#define SENT_C 1.0e6f
#define SENT_W 3.0e12f

// ---------------- kernel 1: fused fwd+rev min-distance ----------------
// blocks [0, fwdBlocks): forward term (simp barycenters vs orig barycenters)
// blocks [fwdBlocks, ..): reverse term (sampled points vs orig vertices)
// Tiles (barycenter / vertex + |.|^2) are computed on the fly from raw inputs.
// Each thread owns P points; per-point min merged across chunk-blocks via
// atomicMin on float bits (values clamped >= 0; arrays pre-set to 0xFFFFFFFF).
__global__ void min_kernel(const float* __restrict__ sverts,
                           const int* __restrict__ sfaces,
                           const float* __restrict__ u1,
                           const float* __restrict__ u2,
                           const float* __restrict__ overts,
                           const int* __restrict__ ofaces,
                           unsigned int* __restrict__ fwd_min,
                           unsigned int* __restrict__ rev_min,
                           int fs, int S,
                           int fwdBlocks, int fwdPtBlocks, int fwdChunk, int f_orig,
                           int revPtBlocks, int revChunk, int n_orig) {
    __shared__ float4 tile[BLK + JU];
    int bid = blockIdx.x;
    int t = threadIdx.x;

    bool isFwd = (bid < fwdBlocks);
    unsigned int* outmin;
    int nsrc, npts, pb, cb, chunk;
    if (isFwd) {
        outmin = fwd_min; nsrc = f_orig; npts = fs;
        pb = bid % fwdPtBlocks; cb = bid / fwdPtBlocks; chunk = fwdChunk;
    } else {
        int b = bid - fwdBlocks;
        outmin = rev_min; nsrc = n_orig; npts = fs * S;
        pb = b % revPtBlocks; cb = b / revPtBlocks; chunk = revChunk;
    }

    // permanent sentinel pad for the prefetch window
    if (t < JU) tile[BLK + t] = make_float4(SENT_C, SENT_C, SENT_C, SENT_W);

    int pbase = pb * BLK * P;
    float px[P], py[P], pz[P], p2[P], m[P];
    bool val[P];
    const float third = 1.0f / 3.0f;

    #pragma unroll
    for (int i = 0; i < P; ++i) {
        int k = pbase + i * BLK + t;
        val[i] = (k < npts);
        float x = 0.f, y = 0.f, z = 0.f;
        if (val[i]) {
            if (isFwd) {
                int a = sfaces[3 * k], b = sfaces[3 * k + 1], c = sfaces[3 * k + 2];
                x = (sverts[3 * a] + sverts[3 * b] + sverts[3 * c]) * third;
                y = (sverts[3 * a + 1] + sverts[3 * b + 1] + sverts[3 * c + 1]) * third;
                z = (sverts[3 * a + 2] + sverts[3 * b + 2] + sverts[3 * c + 2]) * third;
            } else {
                int f = k / S;
                float r1 = sqrtf(u1[k]);
                float uu2 = u2[k];
                float wa = 1.0f - r1;
                float wb = r1 * (1.0f - uu2);
                float wc = r1 * uu2;
                int a = sfaces[3 * f], b = sfaces[3 * f + 1], c = sfaces[3 * f + 2];
                x = wa * sverts[3 * a] + wb * sverts[3 * b] + wc * sverts[3 * c];
                y = wa * sverts[3 * a + 1] + wb * sverts[3 * b + 1] + wc * sverts[3 * c + 1];
                z = wa * sverts[3 * a + 2] + wb * sverts[3 * b + 2] + wc * sverts[3 * c + 2];
            }
        }
        p2[i] = x * x + y * y + z * z;
        px[i] = -2.0f * x;
        py[i] = -2.0f * y;
        pz[i] = -2.0f * z;
        m[i] = __uint_as_float(INFBITS);
    }

    int start = cb * chunk;
    int end = min(start + chunk, nsrc);
    for (int base = start; base < end; base += BLK) {
        int n = min(BLK, end - base);
        __syncthreads();
        if (t < n) {
            int g = base + t;
            float x, y, z;
            if (isFwd) {
                int a = ofaces[3 * g], b = ofaces[3 * g + 1], c = ofaces[3 * g + 2];
                x = (overts[3 * a] + overts[3 * b] + overts[3 * c]) * third;
                y = (overts[3 * a + 1] + overts[3 * b + 1] + overts[3 * c + 1]) * third;
                z = (overts[3 * a + 2] + overts[3 * b + 2] + overts[3 * c + 2]) * third;
            } else {
                x = overts[3 * g];
                y = overts[3 * g + 1];
                z = overts[3 * g + 2];
            }
            tile[t] = make_float4(x, y, z, x * x + y * y + z * z);
        } else {
            tile[t] = make_float4(SENT_C, SENT_C, SENT_C, SENT_W);
        }
        __syncthreads();

        int nit = (n + JU - 1) & ~(JU - 1);
        float4 va = tile[0], vb = tile[1], vc = tile[2], vd = tile[3];
        for (int j = 0; j < nit; j += JU) {
            float4 na = tile[j + 4];
            float4 nb = tile[j + 5];
            float4 nc = tile[j + 6];
            float4 nd = tile[j + 7];
            #pragma unroll
            for (int i = 0; i < P; ++i) {
                float s0 = fmaf(px[i], va.x, va.w);
                s0 = fmaf(py[i], va.y, s0);
                s0 = fmaf(pz[i], va.z, s0);
                float s1 = fmaf(px[i], vb.x, vb.w);
                s1 = fmaf(py[i], vb.y, s1);
                s1 = fmaf(pz[i], vb.z, s1);
                m[i] = fminf(m[i], fminf(s0, s1));   // fusable -> v_min3_f32
                float s2 = fmaf(px[i], vc.x, vc.w);
                s2 = fmaf(py[i], vc.y, s2);
                s2 = fmaf(pz[i], vc.z, s2);
                float s3 = fmaf(px[i], vd.x, vd.w);
                s3 = fmaf(py[i], vd.y, s3);
                s3 = fmaf(pz[i], vd.z, s3);
                m[i] = fminf(m[i], fminf(s2, s3));
            }
            va = na; vb = nb; vc = nc; vd = nd;
        }
    }

    #pragma unroll
    for (int i = 0; i < P; ++i) {
        if (val[i]) {
            float d2 = fmaxf(p2[i] + m[i], 0.0f);
            atomicMin(&outmin[pbase + i * BLK + t], __float_as_uint(d2));
        }
    }
}

// ---------------- kernel 2: reductions + final scalar (last-block writes out) ----------------
__global__ void finalize_kernel(const unsigned int* __restrict__ fwd_min,
                                const unsigned int* __restrict__ rev_min,
                                const float* __restrict__ fp,
                                float* acc, float* out,
                                int fs, int npts, int S, int nblocks) {
    __shared__ float s1[BLK], s2[BLK], s3[BLK];
    int k = blockIdx.x * blockDim.x + threadIdx.x;
    float fsum = 0.f, rsum = 0.f, rmax = 0.f;
    if (k < npts) {
        float md = __uint_as_float(rev_min[k]);
        float p = fp[k / S];
        rsum = p * md;
        rmax = md;
    }
    if (k < fs) {
        float p = fp[k];
        fsum = p * __uint_as_float(fwd_min[k]) + PROB_PENALTYF * (1.0f - p);
    }
    s1[threadIdx.x] = fsum;
    s2[threadIdx.x] = rsum;
    s3[threadIdx.x] = rmax;
    __syncthreads();
    for (int off = BLK / 2; off > 0; off >>= 1) {
        if ((int)threadIdx.x < off) {
            s1[threadIdx.x] += s1[threadIdx.x + off];
            s2[threadIdx.x] += s2[threadIdx.x + off];
            s3[threadIdx.x] = fmaxf(s3[threadIdx.x], s3[threadIdx.x + off]);
        }
        __syncthreads();
    }
    if (threadIdx.x == 0) {
        atomicAdd(&acc[0], s1[0]);
        atomicAdd(&acc[1], s2[0]);
        atomicMax((unsigned int*)&acc[2], __float_as_uint(s3[0]));
        __threadfence();
        unsigned int ticket = atomicAdd((unsigned int*)&acc[3], 1u);
        if (ticket == (unsigned int)(nblocks - 1)) {
            __threadfence();
            float a0 = atomicAdd(&acc[0], 0.0f);          // atomic read at coherence point
            float a1 = atomicAdd(&acc[1], 0.0f);
            unsigned int mb = atomicOr((unsigned int*)&acc[2], 0u);
            out[0] = a0 + a1 * (REV_SCALEF / (__uint_as_float(mb) + EPSF));
        }
    }
}

extern "C" void kernel_launch(void* const* d_in, const int* in_sizes, int n_in,
                              void* d_out, int out_size, void* d_ws, size_t ws_size,
                              hipStream_t stream) {
    const float* overts = (const float*)d_in[0];
    const int*   ofaces = (const int*)d_in[1];
    const float* sverts = (const float*)d_in[2];
    const int*   sfaces = (const int*)d_in[3];
    const float* fp     = (const float*)d_in[4];
    const float* u1     = (const float*)d_in[5];
    const float* u2     = (const float*)d_in[6];
    float* out = (float*)d_out;

    const int N_ORIG = in_sizes[0] / 3;
    const int F_ORIG = in_sizes[1] / 3;
    const int F_SIMP = in_sizes[3] / 3;
    const int S      = in_sizes[5] / F_SIMP;
    const int NPTS   = F_SIMP * S;

    // workspace: acc[16 floats] | fwd_min[F_SIMP] | rev_min[NPTS]
    float* acc = (float*)d_ws;
    unsigned int* fwd_min = (unsigned int*)(acc + 16);
    unsigned int* rev_min = fwd_min + F_SIMP;

    hipMemsetAsync(acc, 0, 16 * sizeof(float), stream);
    hipMemsetAsync(fwd_min, 0xFF, (size_t)(F_SIMP + NPTS) * sizeof(unsigned int), stream);

    // target ~760 uniform blocks (~3 per CU), equal inner-trip for fwd and rev
    const int C = 212;
    const int fwdPtBlocks = (F_SIMP + BLK * P - 1) / (BLK * P);            // 2
    const int fwdChunks   = (F_ORIG + C - 1) / C;                          // 76
    const int fwdChunk    = (F_ORIG + fwdChunks - 1) / fwdChunks;          // 211
    const int fwdBlocks   = fwdPtBlocks * fwdChunks;                       // 152

    const int revPtBlocks = (NPTS + BLK * P - 1) / (BLK * P);              // 16
    const int revChunks   = (N_ORIG + C - 1) / C;                          // 38
    const int revChunk    = (N_ORIG + revChunks - 1) / revChunks;          // 211
    const int revBlocks   = revPtBlocks * revChunks;                       // 608

    hipLaunchKernelGGL(min_kernel, dim3(fwdBlocks + revBlocks), dim3(BLK), 0, stream,
                       sverts, sfaces, u1, u2, overts, ofaces, fwd_min, rev_min,
                       F_SIMP, S,
                       fwdBlocks, fwdPtBlocks, fwdChunk, F_ORIG,
                       revPtBlocks, revChunk, N_ORIG);

    const int finBlocks = (NPTS + BLK - 1) / BLK;
    hipLaunchKernelGGL(finalize_kernel, dim3(finBlocks), dim3(BLK), 0, stream,
                       fwd_min, rev_min, fp, acc, out, F_SIMP, NPTS, S, finBlocks);
}

// Round 4
// 50.415 us; speedup vs baseline: 1.0250x; 1.0250x over previous
//
#include <hip/hip_runtime.h>

#define EPSF 1e-8f
#define PROB_PENALTYF 1e-4f
#define REV_SCALEF 0.1f

#define BLK 256
#define P 8
#define TILE 160          // divides 16000 (fwd sources) and 8000 (rev sources) exactly
#define JU 8
#define INFBITS 0x7F800000u

// sentinel "far away" vertex (only used if nsrc % TILE != 0)
#define SENT_C 1.0e6f
#define SENT_W 3.0e12f

__device__ __forceinline__ float min3f(float a, float b, float c) {
    return fminf(fminf(a, b), c);   // -> v_min3_f32
}

// ---------------- kernel 1: fused fwd+rev min-distance ----------------
// blocks [0, fwdBlocks): forward term (simp barycenters vs orig barycenters)
// blocks [fwdBlocks, ..): reverse term (sampled points vs orig vertices)
// One TILE of sources per block (constant-trip inner loop); each thread owns P
// points; per-point min merged across tile-blocks via atomicMin on float bits
// (values clamped >= 0; arrays pre-set to 0xFFFFFFFF).
__global__ void __launch_bounds__(BLK, 4)
min_kernel(const float* __restrict__ sverts,
           const int* __restrict__ sfaces,
           const float* __restrict__ u1,
           const float* __restrict__ u2,
           const float* __restrict__ overts,
           const int* __restrict__ ofaces,
           unsigned int* __restrict__ fwd_min,
           unsigned int* __restrict__ rev_min,
           int fs, int S,
           int fwdBlocks, int fwdPtBlocks, int f_orig,
           int revPtBlocks, int n_orig) {
    __shared__ float4 tile[TILE];
    int bid = blockIdx.x;
    int t = threadIdx.x;

    bool isFwd = (bid < fwdBlocks);
    unsigned int* outmin;
    int nsrc, npts, pb, cb;
    if (isFwd) {
        outmin = fwd_min; nsrc = f_orig; npts = fs;
        pb = bid % fwdPtBlocks; cb = bid / fwdPtBlocks;
    } else {
        int b = bid - fwdBlocks;
        outmin = rev_min; nsrc = n_orig; npts = fs * S;
        pb = b % revPtBlocks; cb = b / revPtBlocks;
    }
    const float third = 1.0f / 3.0f;

    // ---- stage one tile of sources (with |.|^2 in .w) ----
    if (t < TILE) {
        int g = cb * TILE + t;
        if (g < nsrc) {
            float x, y, z;
            if (isFwd) {
                int a = ofaces[3 * g], b = ofaces[3 * g + 1], c = ofaces[3 * g + 2];
                x = (overts[3 * a] + overts[3 * b] + overts[3 * c]) * third;
                y = (overts[3 * a + 1] + overts[3 * b + 1] + overts[3 * c + 1]) * third;
                z = (overts[3 * a + 2] + overts[3 * b + 2] + overts[3 * c + 2]) * third;
            } else {
                x = overts[3 * g];
                y = overts[3 * g + 1];
                z = overts[3 * g + 2];
            }
            tile[t] = make_float4(x, y, z, x * x + y * y + z * z);
        } else {
            tile[t] = make_float4(SENT_C, SENT_C, SENT_C, SENT_W);
        }
    }

    // ---- per-thread points ----
    int pbase = pb * BLK * P;
    float px[P], py[P], pz[P], p2[P], m[P];
    bool val[P];
    #pragma unroll
    for (int i = 0; i < P; ++i) {
        int k = pbase + i * BLK + t;
        val[i] = (k < npts);
        float x = 0.f, y = 0.f, z = 0.f;
        if (val[i]) {
            if (isFwd) {
                int a = sfaces[3 * k], b = sfaces[3 * k + 1], c = sfaces[3 * k + 2];
                x = (sverts[3 * a] + sverts[3 * b] + sverts[3 * c]) * third;
                y = (sverts[3 * a + 1] + sverts[3 * b + 1] + sverts[3 * c + 1]) * third;
                z = (sverts[3 * a + 2] + sverts[3 * b + 2] + sverts[3 * c + 2]) * third;
            } else {
                int f = k / S;
                float r1 = sqrtf(u1[k]);
                float uu2 = u2[k];
                float wa = 1.0f - r1;
                float wb = r1 * (1.0f - uu2);
                float wc = r1 * uu2;
                int a = sfaces[3 * f], b = sfaces[3 * f + 1], c = sfaces[3 * f + 2];
                x = wa * sverts[3 * a] + wb * sverts[3 * b] + wc * sverts[3 * c];
                y = wa * sverts[3 * a + 1] + wb * sverts[3 * b + 1] + wc * sverts[3 * c + 1];
                z = wa * sverts[3 * a + 2] + wb * sverts[3 * b + 2] + wc * sverts[3 * c + 2];
            }
        }
        p2[i] = x * x + y * y + z * z;
        px[i] = -2.0f * x;
        py[i] = -2.0f * y;
        pz[i] = -2.0f * z;
        m[i] = __uint_as_float(INFBITS);
    }

    __syncthreads();

    // ---- constant-trip inner loop: TILE/JU iterations, JU sources each ----
    for (int j = 0; j < TILE; j += JU) {
        float4 v0 = tile[j + 0];
        float4 v1 = tile[j + 1];
        float4 v2 = tile[j + 2];
        float4 v3 = tile[j + 3];
        float4 v4 = tile[j + 4];
        float4 v5 = tile[j + 5];
        float4 v6 = tile[j + 6];
        float4 v7 = tile[j + 7];
        #pragma unroll
        for (int i = 0; i < P; ++i) {
            float a = px[i], b = py[i], c = pz[i];
            float s0 = fmaf(c, v0.z, fmaf(b, v0.y, fmaf(a, v0.x, v0.w)));
            float s1 = fmaf(c, v1.z, fmaf(b, v1.y, fmaf(a, v1.x, v1.w)));
            float s2 = fmaf(c, v2.z, fmaf(b, v2.y, fmaf(a, v2.x, v2.w)));
            float s3 = fmaf(c, v3.z, fmaf(b, v3.y, fmaf(a, v3.x, v3.w)));
            float s4 = fmaf(c, v4.z, fmaf(b, v4.y, fmaf(a, v4.x, v4.w)));
            float s5 = fmaf(c, v5.z, fmaf(b, v5.y, fmaf(a, v5.x, v5.w)));
            float s6 = fmaf(c, v6.z, fmaf(b, v6.y, fmaf(a, v6.x, v6.w)));
            float s7 = fmaf(c, v7.z, fmaf(b, v7.y, fmaf(a, v7.x, v7.w)));
            float q = m[i];
            q = min3f(q, s0, s1);
            q = min3f(q, s2, s3);
            q = min3f(q, s4, s5);
            q = min3f(q, s6, s7);
            m[i] = q;
        }
    }

    #pragma unroll
    for (int i = 0; i < P; ++i) {
        if (val[i]) {
            float d2 = fmaxf(p2[i] + m[i], 0.0f);
            atomicMin(&outmin[pbase + i * BLK + t], __float_as_uint(d2));
        }
    }
}

// ---------------- kernel 2: reductions + final scalar (last-block writes out) ----------------
__global__ void finalize_kernel(const unsigned int* __restrict__ fwd_min,
                                const unsigned int* __restrict__ rev_min,
                                const float* __restrict__ fp,
                                float* acc, float* out,
                                int fs, int npts, int S, int nblocks) {
    __shared__ float s1[BLK], s2[BLK], s3[BLK];
    int k = blockIdx.x * blockDim.x + threadIdx.x;
    float fsum = 0.f, rsum = 0.f, rmax = 0.f;
    if (k < npts) {
        float md = __uint_as_float(rev_min[k]);
        float p = fp[k / S];
        rsum = p * md;
        rmax = md;
    }
    if (k < fs) {
        float p = fp[k];
        fsum = p * __uint_as_float(fwd_min[k]) + PROB_PENALTYF * (1.0f - p);
    }
    s1[threadIdx.x] = fsum;
    s2[threadIdx.x] = rsum;
    s3[threadIdx.x] = rmax;
    __syncthreads();
    for (int off = BLK / 2; off > 0; off >>= 1) {
        if ((int)threadIdx.x < off) {
            s1[threadIdx.x] += s1[threadIdx.x + off];
            s2[threadIdx.x] += s2[threadIdx.x + off];
            s3[threadIdx.x] = fmaxf(s3[threadIdx.x], s3[threadIdx.x + off]);
        }
        __syncthreads();
    }
    if (threadIdx.x == 0) {
        atomicAdd(&acc[0], s1[0]);
        atomicAdd(&acc[1], s2[0]);
        atomicMax((unsigned int*)&acc[2], __float_as_uint(s3[0]));
        __threadfence();
        unsigned int ticket = atomicAdd((unsigned int*)&acc[3], 1u);
        if (ticket == (unsigned int)(nblocks - 1)) {
            __threadfence();
            float a0 = atomicAdd(&acc[0], 0.0f);
            float a1 = atomicAdd(&acc[1], 0.0f);
            unsigned int mb = atomicOr((unsigned int*)&acc[2], 0u);
            out[0] = a0 + a1 * (REV_SCALEF / (__uint_as_float(mb) + EPSF));
        }
    }
}

extern "C" void kernel_launch(void* const* d_in, const int* in_sizes, int n_in,
                              void* d_out, int out_size, void* d_ws, size_t ws_size,
                              hipStream_t stream) {
    const float* overts = (const float*)d_in[0];
    const int*   ofaces = (const int*)d_in[1];
    const float* sverts = (const float*)d_in[2];
    const int*   sfaces = (const int*)d_in[3];
    const float* fp     = (const float*)d_in[4];
    const float* u1     = (const float*)d_in[5];
    const float* u2     = (const float*)d_in[6];
    float* out = (float*)d_out;

    const int N_ORIG = in_sizes[0] / 3;
    const int F_ORIG = in_sizes[1] / 3;
    const int F_SIMP = in_sizes[3] / 3;
    const int S      = in_sizes[5] / F_SIMP;
    const int NPTS   = F_SIMP * S;

    // workspace: acc[16 floats] | fwd_min[F_SIMP] | rev_min[NPTS]
    float* acc = (float*)d_ws;
    unsigned int* fwd_min = (unsigned int*)(acc + 16);
    unsigned int* rev_min = fwd_min + F_SIMP;

    hipMemsetAsync(acc, 0, 16 * sizeof(float), stream);
    hipMemsetAsync(fwd_min, 0xFF, (size_t)(F_SIMP + NPTS) * sizeof(unsigned int), stream);

    // fwd: 2 point-blocks x 100 tiles = 200 blocks
    // rev: 16 point-blocks x 50 tiles = 800 blocks  -> 1000 blocks (~3.9/CU)
    const int fwdPtBlocks = (F_SIMP + BLK * P - 1) / (BLK * P);
    const int fwdTiles    = (F_ORIG + TILE - 1) / TILE;
    const int fwdBlocks   = fwdPtBlocks * fwdTiles;

    const int revPtBlocks = (NPTS + BLK * P - 1) / (BLK * P);
    const int revTiles    = (N_ORIG + TILE - 1) / TILE;
    const int revBlocks   = revPtBlocks * revTiles;

    hipLaunchKernelGGL(min_kernel, dim3(fwdBlocks + revBlocks), dim3(BLK), 0, stream,
                       sverts, sfaces, u1, u2, overts, ofaces, fwd_min, rev_min,
                       F_SIMP, S,
                       fwdBlocks, fwdPtBlocks, F_ORIG,
                       revPtBlocks, N_ORIG);

    const int finBlocks = (NPTS + BLK - 1) / BLK;
    hipLaunchKernelGGL(finalize_kernel, dim3(finBlocks), dim3(BLK), 0, stream,
                       fwd_min, rev_min, fp, acc, out, F_SIMP, NPTS, S, finBlocks);
}